// Round 5
// baseline (11563.803 us; speedup 1.0000x reference)
//
#include <hip/hip_runtime.h>
#include <math.h>

#define S_LEN 4096
#define NTAG 20
#define TAG_STOP 19
#define NEGV -10000.0f

// ---------------- workspace layout (bytes) ----------------
// [4096,20480)     ull h_pub[2][2][512]   (dir, parity, unit) packed {seq32|h32}
// [65536, +64MB)   float pre[4096][4096]  (pos, row; rows 0..2047 fwd, 2048..4095 bwd)
// then             float hs[2][4096][512]
// then             float feats[4096][20]
// then             u8 bptr[4096*20]

__global__ void init_ws(unsigned long long* hpub) {
    int i = blockIdx.x * 256 + threadIdx.x;
    if (i < 2048) hpub[i] = 0ull;
}

__device__ __forceinline__ float sigm(float x) { return 1.0f / (1.0f + expf(-x)); }

// ---------------- kernel A: embed gather + input GEMM (fp32) ----------------
__launch_bounds__(256)
__global__ void pre_gemm(const int* __restrict__ sent, const float* __restrict__ embed,
                         const float* __restrict__ wf, const float* __restrict__ wb,
                         const float* __restrict__ bihf, const float* __restrict__ bhhf,
                         const float* __restrict__ bihb, const float* __restrict__ bhhb,
                         float* __restrict__ pre)
{
    __shared__ float As[16][68];
    __shared__ float Bs[16][136];
    __shared__ int   srow[64];
    const int tid = threadIdx.x;
    const int bm = blockIdx.x & 63;
    const int bn = blockIdx.x >> 6;
    const int pos0 = bm * 64, row0 = bn * 128;
    if (tid < 64) srow[tid] = sent[pos0 + tid];
    __syncthreads();

    const int tx = tid & 15, ty = tid >> 4;
    float acc[4][8];
    #pragma unroll
    for (int m = 0; m < 4; ++m)
        #pragma unroll
        for (int n = 0; n < 8; ++n) acc[m][n] = 0.f;

    for (int kt = 0; kt < 1024; kt += 16) {
        {
            int m = tid >> 2, kc = (tid & 3) * 4;
            const float* src = embed + (size_t)srow[m] * 1024 + kt + kc;
            float4 v = *(const float4*)src;
            As[kc+0][m] = v.x; As[kc+1][m] = v.y; As[kc+2][m] = v.z; As[kc+3][m] = v.w;
        }
        #pragma unroll
        for (int it = 0; it < 2; ++it) {
            int n = (tid >> 2) + it * 64;
            int kc = (tid & 3) * 4;
            int grow = row0 + n;
            const float* wsrc = (grow < 2048) ? (wf + (size_t)grow * 1024)
                                              : (wb + (size_t)(grow - 2048) * 1024);
            float4 v = *(const float4*)(wsrc + kt + kc);
            Bs[kc+0][n] = v.x; Bs[kc+1][n] = v.y; Bs[kc+2][n] = v.z; Bs[kc+3][n] = v.w;
        }
        __syncthreads();
        #pragma unroll
        for (int kk = 0; kk < 16; ++kk) {
            float a[4], b[8];
            float4 av = *(const float4*)&As[kk][ty * 4];
            a[0] = av.x; a[1] = av.y; a[2] = av.z; a[3] = av.w;
            float4 bv0 = *(const float4*)&Bs[kk][tx * 8];
            float4 bv1 = *(const float4*)&Bs[kk][tx * 8 + 4];
            b[0]=bv0.x; b[1]=bv0.y; b[2]=bv0.z; b[3]=bv0.w;
            b[4]=bv1.x; b[5]=bv1.y; b[6]=bv1.z; b[7]=bv1.w;
            #pragma unroll
            for (int m = 0; m < 4; ++m)
                #pragma unroll
                for (int n = 0; n < 8; ++n) acc[m][n] += a[m] * b[n];
        }
        __syncthreads();
    }
    #pragma unroll
    for (int m = 0; m < 4; ++m) {
        int pos = pos0 + ty * 4 + m;
        #pragma unroll
        for (int n = 0; n < 8; ++n) {
            int grow = row0 + tx * 8 + n;
            float bias = (grow < 2048) ? (bihf[grow] + bhhf[grow])
                                       : (bihb[grow - 2048] + bhhb[grow - 2048]);
            pre[(size_t)pos * 4096 + grow] = acc[m][n] + bias;
        }
    }
}

// ---------------- one LSTM step (P = s&1, compile-time) ----------------
// stage(s) fills buf[P] with h_{s-1}; end of step s publishes tag s+1 into
// pub[P^1] (lane 0 of unit-group) and own-unit h into buf[P^1] (lane 16).
template<int P>
__device__ __forceinline__ void lstm_step(
    int s, int dir, int wg, int j, int hf, int ks,
    bool isPoller, int p, bool own, int sidx, bool glane,
    const float* __restrict__ pre, const float* __restrict__ h0,
    float* __restrict__ hs, unsigned long long* pub,
    float (&buf)[2][576],
    const float (&wr0)[32], const float (&wr1)[32],
    float (&pf)[4], float& c_reg)
{
    // ---- stage h_{s-1} into buf[P]: one 8B data-is-flag poll per poller ----
    if (s == 0) {
        if (isPoller) buf[0][sidx] = h0[dir * 512 + p];
    } else if (isPoller && !own) {
        const unsigned int expect = (unsigned int)s;
        unsigned long long u = __hip_atomic_load(&pub[P * 512 + p],
                                                 __ATOMIC_RELAXED, __HIP_MEMORY_SCOPE_AGENT);
        while ((unsigned int)(u >> 32) < expect)
            u = __hip_atomic_load(&pub[P * 512 + p],
                                  __ATOMIC_RELAXED, __HIP_MEMORY_SCOPE_AGENT);
        buf[P][sidx] = __uint_as_float((unsigned int)u);
    }
    __syncthreads();   // the only barrier per step

    // ---- matvec: 2 gate rows x 32 k per lane, weights in VGPRs ----
    float a0 = 0.f, a1 = 0.f;
    const float* hp = &buf[P][ks * 36];
    #pragma unroll
    for (int q = 0; q < 8; ++q) {
        float4 h4 = ((const float4*)hp)[q];
        a0 += wr0[q*4+0]*h4.x + wr0[q*4+1]*h4.y + wr0[q*4+2]*h4.z + wr0[q*4+3]*h4.w;
        a1 += wr1[q*4+0]*h4.x + wr1[q*4+1]*h4.y + wr1[q*4+2]*h4.z + wr1[q*4+3]*h4.w;
    }
    // ---- 16-lane butterfly reduce over k-slices ----
    a0 += __shfl_xor(a0, 1); a0 += __shfl_xor(a0, 2); a0 += __shfl_xor(a0, 4); a0 += __shfl_xor(a0, 8);
    a1 += __shfl_xor(a1, 1); a1 += __shfl_xor(a1, 2); a1 += __shfl_xor(a1, 4); a1 += __shfl_xor(a1, 8);
    // ---- cross-half swap: lane gets the other half's two sums ----
    float b0 = __shfl_xor(a0, 16);
    float b1 = __shfl_xor(a1, 16);

    // ---- gates (computed redundantly on lanes 0 and 16 of each unit-group) ----
    if (glane) {
        float gi, gf, gg, go;
        if (hf == 0) { gi = a0 + pf[0]; gf = a1 + pf[1]; gg = b0 + pf[2]; go = b1 + pf[3]; }
        else         { gi = b0 + pf[0]; gf = b1 + pf[1]; gg = a0 + pf[2]; go = a1 + pf[3]; }
        float cn = sigm(gf) * c_reg + sigm(gi) * tanhf(gg);
        float hN = sigm(go) * tanhf(cn);
        c_reg = cn;
        if (hf == 0) {
            // publisher lane: ONLY the agent-scope publish (no other outstanding VMEM)
            unsigned long long uv = ((unsigned long long)(unsigned int)(s + 1) << 32)
                                  | (unsigned long long)__float_as_uint(hN);
            __hip_atomic_store(&pub[(P ^ 1) * 512 + j], uv,
                               __ATOMIC_RELAXED, __HIP_MEMORY_SCOPE_AGENT);
        } else {
            // writer lane: hs output + own-unit LDS fast path (next parity)
            const int pos = dir ? (S_LEN - 1 - s) : s;
            hs[((size_t)dir * S_LEN + pos) * 512 + j] = hN;
            buf[P ^ 1][j + 4 * wg] = hN;
        }
        // ---- distance-2 pre prefetch for step s+2 (both gate lanes) ----
        if (s + 2 < S_LEN) {
            const int pp = dir ? (S_LEN - 3 - s) : (s + 2);
            const float* pb = pre + (size_t)pp * 4096 + dir * 2048 + j;
            pf[0] = pb[0]; pf[1] = pb[512]; pf[2] = pb[1024]; pf[3] = pb[1536];
        }
    }
}

// ---------------- kernel B: bidirectional LSTM ----------------
// 32 blocks x 1024 threads. blocks 0..15 = fwd, 16..31 = bwd. Block owns 32
// units; each 32-lane group computes 1 unit: lanes split into 2 halves (gates
// i,f / g,o), each lane 2 gate rows x 32 k = 64 weight floats -> VGPR-resident
// under __launch_bounds__(1024,4)'s 128-reg cap (no AGPR round-trips).
// Pollers are lanes ks in [1,8] of each half (512/block, disjoint from the
// publisher lane 0 and writer lane 16 of each group).
__launch_bounds__(1024, 4)
__global__ void lstm_kernel(const float* __restrict__ pre,
                            const float* __restrict__ w_hh_f, const float* __restrict__ w_hh_b,
                            const float* __restrict__ h0, const float* __restrict__ c0,
                            float* __restrict__ hs, unsigned long long* __restrict__ h_pub)
{
    const int dir  = blockIdx.x >> 4;
    const int wg   = blockIdx.x & 15;
    const int tid  = threadIdx.x;
    const int g    = tid >> 5;           // unit group 0..31
    const int hf   = (tid >> 4) & 1;     // 0: gates i,f   1: gates g,o
    const int ks   = tid & 15;           // k-slice
    const int j    = wg * 32 + g;        // global unit
    const float* w_hh = dir ? w_hh_b : w_hh_f;

    __shared__ float buf[2][576];        // double-buffered h, pad 4 per 32

    // ---- weights: 2 gate rows ((2hf)*512+j, (2hf+1)*512+j) x 32 k, 64 f32 in VGPRs ----
    float wr0[32], wr1[32];
    {
        const float* wbase = w_hh + ((size_t)(hf * 2) * 512 + j) * 512 + ks * 32;
        #pragma unroll
        for (int q = 0; q < 8; ++q) {
            float4 v0 = *(const float4*)(wbase + q * 4);
            wr0[q*4+0] = v0.x; wr0[q*4+1] = v0.y; wr0[q*4+2] = v0.z; wr0[q*4+3] = v0.w;
            float4 v1 = *(const float4*)(wbase + 262144 + q * 4);
            wr1[q*4+0] = v1.x; wr1[q*4+1] = v1.y; wr1[q*4+2] = v1.z; wr1[q*4+3] = v1.w;
        }
    }

    const bool glane = (ks == 0);
    float c_reg = 0.f;
    float pfA[4] = {0,0,0,0}, pfB[4] = {0,0,0,0};
    if (glane) {
        c_reg = c0[dir * 512 + j];
        const int p0 = dir ? (S_LEN - 1) : 0;
        const int p1 = dir ? (S_LEN - 2) : 1;
        const float* b0 = pre + (size_t)p0 * 4096 + dir * 2048 + j;
        const float* b1 = pre + (size_t)p1 * 4096 + dir * 2048 + j;
        pfA[0] = b0[0]; pfA[1] = b0[512]; pfA[2] = b0[1024]; pfA[3] = b0[1536];
        pfB[0] = b1[0]; pfB[1] = b1[512]; pfB[2] = b1[1024]; pfB[3] = b1[1536];
    }

    // ---- poller mapping: lanes ks in [1,8] of each half -> 512 pollers ----
    const int  ksm      = ks - 1;
    const bool isPoller = (ksm >= 0 && ksm < 8);
    const int  p        = g * 16 + hf * 8 + (ksm & 7);    // staged unit, 0..511
    const bool own      = ((p >> 5) == wg);               // own units via LDS fast path
    const int  sidx     = p + ((p >> 5) << 2);            // padded LDS index
    unsigned long long* pub = h_pub + dir * 1024;

    for (int s = 0; s < S_LEN; s += 2) {
        lstm_step<0>(s,     dir, wg, j, hf, ks, isPoller, p, own, sidx, glane,
                     pre, h0, hs, pub, buf, wr0, wr1, pfA, c_reg);
        lstm_step<1>(s + 1, dir, wg, j, hf, ks, isPoller, p, own, sidx, glane,
                     pre, h0, hs, pub, buf, wr0, wr1, pfB, c_reg);
    }
}

// ---------------- kernel C: feats = concat(hf,hb) @ w_out^T + b_out ----------------
__launch_bounds__(256)
__global__ void feats_kernel(const float* __restrict__ hs, const float* __restrict__ w_out,
                             const float* __restrict__ b_out, float* __restrict__ feats)
{
    const int pos = blockIdx.x;
    const int tid = threadIdx.x;
    __shared__ float hbuf[1024];
    __shared__ float red[160];
    {
        const float* hf = hs + (size_t)pos * 512;
        const float* hb = hs + ((size_t)S_LEN + pos) * 512;
        if (tid < 128) *(float4*)&hbuf[tid * 4]           = *(const float4*)&hf[tid * 4];
        else           *(float4*)&hbuf[512 + (tid-128)*4] = *(const float4*)&hb[(tid - 128) * 4];
    }
    __syncthreads();
    if (tid < 160) {
        int tag = tid >> 3, part = tid & 7;
        const float* wrow = w_out + (size_t)tag * 1024 + part * 128;
        const float* hrow = hbuf + part * 128;
        float sum = 0.f;
        #pragma unroll
        for (int q = 0; q < 32; ++q) {
            float4 a = ((const float4*)hrow)[q];
            float4 b = ((const float4*)wrow)[q];
            sum += a.x*b.x + a.y*b.y + a.z*b.z + a.w*b.w;
        }
        red[tid] = sum;
    }
    __syncthreads();
    if (tid < NTAG) {
        float sum = b_out[tid];
        #pragma unroll
        for (int pq = 0; pq < 8; ++pq) sum += red[tid * 8 + pq];
        feats[(size_t)pos * NTAG + tid] = sum;
    }
}

// ---------------- kernel D: Viterbi forward + chunked backtrace ----------------
__launch_bounds__(256)
__global__ void viterbi_kernel(const float* __restrict__ feats, const float* __restrict__ trans,
                               unsigned char* __restrict__ bptr, float* __restrict__ out)
{
    __shared__ float feat_lds[64 * NTAG];
    __shared__ int sh_best;
    __shared__ unsigned char Mmap[8][NTAG];
    __shared__ unsigned char entry_s[8];
    const int tid = threadIdx.x;

    if (tid < 64) {
        const int lane = tid;
        const int i = (lane < NTAG) ? lane : (NTAG - 1);
        float trow[NTAG];
        #pragma unroll
        for (int jj = 0; jj < NTAG; ++jj) trow[jj] = trans[i * NTAG + jj];
        float fv[NTAG];
        #pragma unroll
        for (int jj = 0; jj < NTAG; ++jj) fv[jj] = (jj == 18) ? 0.f : NEGV;

        for (int blk = 0; blk < 64; ++blk) {
            #pragma unroll
            for (int q = 0; q < 20; ++q)
                feat_lds[q * 64 + lane] = feats[blk * 1280 + q * 64 + lane];
            for (int ss = 0; ss < 64; ++ss) {
                int s = blk * 64 + ss;
                float best = fv[0] + trow[0];
                int bj = 0;
                #pragma unroll
                for (int jj = 1; jj < NTAG; ++jj) {
                    float cand = fv[jj] + trow[jj];
                    if (cand > best) { best = cand; bj = jj; }   // strict >: first-max tie rule
                }
                float fnew = best + feat_lds[ss * NTAG + i];
                if (lane < NTAG) bptr[s * NTAG + lane] = (unsigned char)bj;
                #pragma unroll
                for (int jj = 0; jj < NTAG; ++jj) fv[jj] = __shfl(fnew, jj);
            }
        }
        if (lane == 0) {
            float best = -1e30f; int bt = 0;
            for (int jj = 0; jj < NTAG; ++jj) {
                float t2 = fv[jj] + trans[TAG_STOP * NTAG + jj];
                if (t2 > best) { best = t2; bt = jj; }
            }
            out[0] = best;
            sh_best = bt;
        }
    }
    __syncthreads();
    if (tid < 160) {
        int c = tid / NTAG, e = tid % NTAG;
        int tag = e;
        for (int t = (c + 1) * 512 - 1; t >= c * 512; --t) tag = bptr[t * NTAG + tag];
        Mmap[c][e] = (unsigned char)tag;
    }
    __syncthreads();
    if (tid == 0) {
        int e = sh_best;
        entry_s[7] = (unsigned char)e;
        for (int c = 7; c >= 1; --c) { e = Mmap[c][e]; entry_s[c - 1] = (unsigned char)e; }
    }
    __syncthreads();
    if (tid < 8) {
        int c = tid;
        int tag = entry_s[c];
        out[1 + (c + 1) * 512 - 1] = (float)tag;
        for (int t = (c + 1) * 512 - 1; t > c * 512; --t) {
            tag = bptr[t * NTAG + tag];
            out[1 + t - 1] = (float)tag;
        }
    }
}

extern "C" void kernel_launch(void* const* d_in, const int* in_sizes, int n_in,
                              void* d_out, int out_size, void* d_ws, size_t ws_size,
                              hipStream_t stream) {
    (void)in_sizes; (void)n_in; (void)out_size; (void)ws_size;
    const int*   sent  = (const int*)d_in[0];
    const float* embed = (const float*)d_in[1];
    const float* wihf  = (const float*)d_in[2];
    const float* whhf  = (const float*)d_in[3];
    const float* bihf  = (const float*)d_in[4];
    const float* bhhf  = (const float*)d_in[5];
    const float* wihb  = (const float*)d_in[6];
    const float* whhb  = (const float*)d_in[7];
    const float* bihb  = (const float*)d_in[8];
    const float* bhhb  = (const float*)d_in[9];
    const float* wout  = (const float*)d_in[10];
    const float* bout  = (const float*)d_in[11];
    const float* trans = (const float*)d_in[12];
    const float* h0    = (const float*)d_in[13];
    const float* c0    = (const float*)d_in[14];

    char* ws = (char*)d_ws;
    unsigned long long* h_pub = (unsigned long long*)(ws + 4096);   // 16 KB
    float* pre   = (float*)(ws + 65536);
    float* hs    = (float*)(ws + 65536 + (size_t)4096 * 4096 * 4);
    float* feats = (float*)(ws + 65536 + (size_t)4096 * 4096 * 4 + (size_t)2 * 4096 * 512 * 4);
    unsigned char* bptr = (unsigned char*)(feats + (size_t)S_LEN * NTAG);
    float* out = (float*)d_out;

    hipLaunchKernelGGL(init_ws, dim3(8), dim3(256), 0, stream, h_pub);
    hipLaunchKernelGGL(pre_gemm, dim3(2048), dim3(256), 0, stream,
                       sent, embed, wihf, wihb, bihf, bhhf, bihb, bhhb, pre);
    hipLaunchKernelGGL(lstm_kernel, dim3(32), dim3(1024), 0, stream,
                       pre, whhf, whhb, h0, c0, hs, h_pub);
    hipLaunchKernelGGL(feats_kernel, dim3(S_LEN), dim3(256), 0, stream,
                       hs, wout, bout, feats);
    hipLaunchKernelGGL(viterbi_kernel, dim3(1), dim3(256), 0, stream,
                       feats, trans, bptr, out);
}

// Round 6
// 11253.917 us; speedup vs baseline: 1.0275x; 1.0275x over previous
//
#include <hip/hip_runtime.h>
#include <math.h>

#define S_LEN 4096
#define NTAG 20
#define TAG_STOP 19
#define NEGV -10000.0f

// ---------------- workspace layout (bytes) ----------------
// [4096,20480)     ull h_pub[2][2][512]   (dir, parity, unit) packed {seq32|h32}
// [65536, +64MB)   float pre[4096][4096]  (pos, row; rows 0..2047 fwd, 2048..4095 bwd)
// then             float hs[2][4096][512]
// then             float feats[4096][20]
// then             u8 bptr[4096*20]

__global__ void init_ws(unsigned long long* hpub) {
    int i = blockIdx.x * 256 + threadIdx.x;
    if (i < 2048) hpub[i] = 0ull;
}

__device__ __forceinline__ float sigm(float x) { return 1.0f / (1.0f + expf(-x)); }

// ---------------- kernel A: embed gather + input GEMM (fp32) ----------------
__launch_bounds__(256)
__global__ void pre_gemm(const int* __restrict__ sent, const float* __restrict__ embed,
                         const float* __restrict__ wf, const float* __restrict__ wb,
                         const float* __restrict__ bihf, const float* __restrict__ bhhf,
                         const float* __restrict__ bihb, const float* __restrict__ bhhb,
                         float* __restrict__ pre)
{
    __shared__ float As[16][68];
    __shared__ float Bs[16][136];
    __shared__ int   srow[64];
    const int tid = threadIdx.x;
    const int bm = blockIdx.x & 63;
    const int bn = blockIdx.x >> 6;
    const int pos0 = bm * 64, row0 = bn * 128;
    if (tid < 64) srow[tid] = sent[pos0 + tid];
    __syncthreads();

    const int tx = tid & 15, ty = tid >> 4;
    float acc[4][8];
    #pragma unroll
    for (int m = 0; m < 4; ++m)
        #pragma unroll
        for (int n = 0; n < 8; ++n) acc[m][n] = 0.f;

    for (int kt = 0; kt < 1024; kt += 16) {
        {
            int m = tid >> 2, kc = (tid & 3) * 4;
            const float* src = embed + (size_t)srow[m] * 1024 + kt + kc;
            float4 v = *(const float4*)src;
            As[kc+0][m] = v.x; As[kc+1][m] = v.y; As[kc+2][m] = v.z; As[kc+3][m] = v.w;
        }
        #pragma unroll
        for (int it = 0; it < 2; ++it) {
            int n = (tid >> 2) + it * 64;
            int kc = (tid & 3) * 4;
            int grow = row0 + n;
            const float* wsrc = (grow < 2048) ? (wf + (size_t)grow * 1024)
                                              : (wb + (size_t)(grow - 2048) * 1024);
            float4 v = *(const float4*)(wsrc + kt + kc);
            Bs[kc+0][n] = v.x; Bs[kc+1][n] = v.y; Bs[kc+2][n] = v.z; Bs[kc+3][n] = v.w;
        }
        __syncthreads();
        #pragma unroll
        for (int kk = 0; kk < 16; ++kk) {
            float a[4], b[8];
            float4 av = *(const float4*)&As[kk][ty * 4];
            a[0] = av.x; a[1] = av.y; a[2] = av.z; a[3] = av.w;
            float4 bv0 = *(const float4*)&Bs[kk][tx * 8];
            float4 bv1 = *(const float4*)&Bs[kk][tx * 8 + 4];
            b[0]=bv0.x; b[1]=bv0.y; b[2]=bv0.z; b[3]=bv0.w;
            b[4]=bv1.x; b[5]=bv1.y; b[6]=bv1.z; b[7]=bv1.w;
            #pragma unroll
            for (int m = 0; m < 4; ++m)
                #pragma unroll
                for (int n = 0; n < 8; ++n) acc[m][n] += a[m] * b[n];
        }
        __syncthreads();
    }
    #pragma unroll
    for (int m = 0; m < 4; ++m) {
        int pos = pos0 + ty * 4 + m;
        #pragma unroll
        for (int n = 0; n < 8; ++n) {
            int grow = row0 + tx * 8 + n;
            float bias = (grow < 2048) ? (bihf[grow] + bhhf[grow])
                                       : (bihb[grow - 2048] + bhhb[grow - 2048]);
            pre[(size_t)pos * 4096 + grow] = acc[m][n] + bias;
        }
    }
}

__device__ __forceinline__ unsigned long long agent_ld(const unsigned long long* p) {
    return __hip_atomic_load(p, __ATOMIC_RELAXED, __HIP_MEMORY_SCOPE_AGENT);
}

// ---------------- one LSTM step (P = s&1, compile-time) ----------------
// stage(s) fills buf[P] with h_{s-1}; publish(s) -> pub[P^1] with tag s+1 and
// own-unit LDS write into buf[P^1] (next step's read buffer).
template<int P>
__device__ __forceinline__ void lstm_step(
    int s, int dir, int wg, int j, int ks, int su, bool own, int sidx, bool gate,
    const float* __restrict__ pre, const float* __restrict__ h0,
    float* __restrict__ hs, unsigned long long* pub,
    float (&buf)[2][576],
    const float (&wr0)[32], const float (&wr1)[32],
    const float (&wr2)[32], const float (&wr3)[32],
    float (&pf)[4], float& c_reg)
{
    // ---- stage h_{s-1} into buf[P]: 2-slot staggered poll (RTT/2 sampling) ----
    if (s == 0) {
        buf[0][sidx] = h0[dir * 512 + su];
    } else if (!own) {
        const unsigned int expect = (unsigned int)s;
        const unsigned long long* p = &pub[P * 512 + su];
        unsigned long long u  = agent_ld(p);
        if ((unsigned int)(u >> 32) < expect) {
            unsigned long long u2 = agent_ld(p);        // slot 2 in flight
            while (true) {
                if ((unsigned int)(u >> 32) >= expect) break;       // test slot1 (vmcnt(1))
                u = agent_ld(p);                                    // refill slot1
                if ((unsigned int)(u2 >> 32) >= expect) { u = u2; break; }  // test slot2
                u2 = agent_ld(p);                                   // refill slot2
            }
        }
        buf[P][sidx] = __uint_as_float((unsigned int)u);
    }
    __syncthreads();   // the only barrier per step

    // ---- matvec: 4 gate rows x 32 k per lane, weights register-resident ----
    float a0 = 0.f, a1 = 0.f, a2 = 0.f, a3 = 0.f;
    const float* hp = &buf[P][ks * 36];
    #pragma unroll
    for (int q = 0; q < 8; ++q) {
        float4 h4 = ((const float4*)hp)[q];
        a0 += wr0[q*4+0]*h4.x + wr0[q*4+1]*h4.y + wr0[q*4+2]*h4.z + wr0[q*4+3]*h4.w;
        a1 += wr1[q*4+0]*h4.x + wr1[q*4+1]*h4.y + wr1[q*4+2]*h4.z + wr1[q*4+3]*h4.w;
        a2 += wr2[q*4+0]*h4.x + wr2[q*4+1]*h4.y + wr2[q*4+2]*h4.z + wr2[q*4+3]*h4.w;
        a3 += wr3[q*4+0]*h4.x + wr3[q*4+1]*h4.y + wr3[q*4+2]*h4.z + wr3[q*4+3]*h4.w;
    }
    // ---- 16-lane butterfly reduce over k-slices ----
    a0 += __shfl_xor(a0, 1); a0 += __shfl_xor(a0, 2); a0 += __shfl_xor(a0, 4); a0 += __shfl_xor(a0, 8);
    a1 += __shfl_xor(a1, 1); a1 += __shfl_xor(a1, 2); a1 += __shfl_xor(a1, 4); a1 += __shfl_xor(a1, 8);
    a2 += __shfl_xor(a2, 1); a2 += __shfl_xor(a2, 2); a2 += __shfl_xor(a2, 4); a2 += __shfl_xor(a2, 8);
    a3 += __shfl_xor(a3, 1); a3 += __shfl_xor(a3, 2); a3 += __shfl_xor(a3, 4); a3 += __shfl_xor(a3, 8);

    // ---- gates + publish (lane ks==0 of each 16-group: 1 unit) ----
    if (gate) {
        float gi = a0 + pf[0], gf = a1 + pf[1], gg = a2 + pf[2], go = a3 + pf[3];
        float cn = sigm(gf) * c_reg + sigm(gi) * tanhf(gg);
        float hN = sigm(go) * tanhf(cn);
        c_reg = cn;
        // publish FIRST: the agent store is the cross-block critical path
        unsigned long long uv = ((unsigned long long)(unsigned int)(s + 1) << 32)
                              | (unsigned long long)__float_as_uint(hN);
        __hip_atomic_store(&pub[(P ^ 1) * 512 + j], uv,
                           __ATOMIC_RELAXED, __HIP_MEMORY_SCOPE_AGENT);
        // then the off-critical-path writes
        const int pos = dir ? (S_LEN - 1 - s) : s;
        hs[((size_t)dir * S_LEN + pos) * 512 + j] = hN;
        buf[P ^ 1][j + 4 * wg] = hN;                    // own-unit fast path (next parity)
        // ---- distance-2 pre prefetch for step s+2 ----
        if (s + 2 < S_LEN) {
            const int pp = dir ? (S_LEN - 3 - s) : (s + 2);
            const float* pb = pre + (size_t)pp * 4096 + dir * 2048 + j;
            pf[0] = pb[0]; pf[1] = pb[512]; pf[2] = pb[1024]; pf[3] = pb[1536];
        }
    }
}

// ---------------- kernel B: bidirectional LSTM ----------------
// 32 blocks x 512 threads (8 waves). blocks 0..15 = fwd, 16..31 = bwd.
// Block owns 32 units (128 gate rows). Lane-group (16 lanes) computes 1 unit:
// 4 gate rows x 32 k each -> 128 weight floats/lane (register-resident across
// the unified VGPR/AGPR file). Each thread stages exactly ONE unit per step via
// a 2-slot staggered data-is-flag agent atomic poll.
__launch_bounds__(512, 2)
__global__ void lstm_kernel(const float* __restrict__ pre,
                            const float* __restrict__ w_hh_f, const float* __restrict__ w_hh_b,
                            const float* __restrict__ h0, const float* __restrict__ c0,
                            float* __restrict__ hs, unsigned long long* __restrict__ h_pub)
{
    const int dir  = blockIdx.x >> 4;
    const int wg   = blockIdx.x & 15;
    const int tid  = threadIdx.x;
    const int wv   = tid >> 6;
    const int lane = tid & 63;
    const int rg   = lane >> 4;
    const int ks   = lane & 15;
    const int j    = wg * 32 + wv * 4 + rg;        // this lane-group's global unit
    const float* w_hh = dir ? w_hh_b : w_hh_f;

    __shared__ float buf[2][576];   // double-buffered h, pad 4 per 32

    // ---- weights: 4 gate rows (g*512+j) x 32 k (ks slice), 128 f32 ----
    float wr0[32], wr1[32], wr2[32], wr3[32];
    {
        const float* wbase = w_hh + (size_t)j * 512 + ks * 32;
        #pragma unroll
        for (int q = 0; q < 8; ++q) {
            float4 v0 = *(const float4*)(wbase + 0 * 262144 + q * 4);
            wr0[q*4+0] = v0.x; wr0[q*4+1] = v0.y; wr0[q*4+2] = v0.z; wr0[q*4+3] = v0.w;
            float4 v1 = *(const float4*)(wbase + 1 * 262144 + q * 4);
            wr1[q*4+0] = v1.x; wr1[q*4+1] = v1.y; wr1[q*4+2] = v1.z; wr1[q*4+3] = v1.w;
            float4 v2 = *(const float4*)(wbase + 2 * 262144 + q * 4);
            wr2[q*4+0] = v2.x; wr2[q*4+1] = v2.y; wr2[q*4+2] = v2.z; wr2[q*4+3] = v2.w;
            float4 v3 = *(const float4*)(wbase + 3 * 262144 + q * 4);
            wr3[q*4+0] = v3.x; wr3[q*4+1] = v3.y; wr3[q*4+2] = v3.z; wr3[q*4+3] = v3.w;
        }
    }

    const bool gate = (ks == 0);
    float c_reg = 0.f;
    float pfA[4] = {0,0,0,0}, pfB[4] = {0,0,0,0};
    if (gate) {
        c_reg = c0[dir * 512 + j];
        const int p0 = dir ? (S_LEN - 1) : 0;
        const int p1 = dir ? (S_LEN - 2) : 1;
        const float* b0 = pre + (size_t)p0 * 4096 + dir * 2048 + j;
        const float* b1 = pre + (size_t)p1 * 4096 + dir * 2048 + j;
        pfA[0] = b0[0]; pfA[1] = b0[512]; pfA[2] = b0[1024]; pfA[3] = b0[1536];
        pfB[0] = b1[0]; pfB[1] = b1[512]; pfB[2] = b1[1024]; pfB[3] = b1[1536];
    }

    const int  su   = tid;                       // unit staged by this thread
    const bool own  = ((su >> 5) == wg);         // own units come via LDS fast path
    const int  sidx = su + ((su >> 5) << 2);     // padded LDS index
    unsigned long long* pub = h_pub + dir * 1024;

    for (int s = 0; s < S_LEN; s += 2) {
        lstm_step<0>(s,     dir, wg, j, ks, su, own, sidx, gate,
                     pre, h0, hs, pub, buf, wr0, wr1, wr2, wr3, pfA, c_reg);
        lstm_step<1>(s + 1, dir, wg, j, ks, su, own, sidx, gate,
                     pre, h0, hs, pub, buf, wr0, wr1, wr2, wr3, pfB, c_reg);
    }
}

// ---------------- kernel C: feats = concat(hf,hb) @ w_out^T + b_out ----------------
__launch_bounds__(256)
__global__ void feats_kernel(const float* __restrict__ hs, const float* __restrict__ w_out,
                             const float* __restrict__ b_out, float* __restrict__ feats)
{
    const int pos = blockIdx.x;
    const int tid = threadIdx.x;
    __shared__ float hbuf[1024];
    __shared__ float red[160];
    {
        const float* hf = hs + (size_t)pos * 512;
        const float* hb = hs + ((size_t)S_LEN + pos) * 512;
        if (tid < 128) *(float4*)&hbuf[tid * 4]           = *(const float4*)&hf[tid * 4];
        else           *(float4*)&hbuf[512 + (tid-128)*4] = *(const float4*)&hb[(tid - 128) * 4];
    }
    __syncthreads();
    if (tid < 160) {
        int tag = tid >> 3, part = tid & 7;
        const float* wrow = w_out + (size_t)tag * 1024 + part * 128;
        const float* hrow = hbuf + part * 128;
        float sum = 0.f;
        #pragma unroll
        for (int q = 0; q < 32; ++q) {
            float4 a = ((const float4*)hrow)[q];
            float4 b = ((const float4*)wrow)[q];
            sum += a.x*b.x + a.y*b.y + a.z*b.z + a.w*b.w;
        }
        red[tid] = sum;
    }
    __syncthreads();
    if (tid < NTAG) {
        float sum = b_out[tid];
        #pragma unroll
        for (int pq = 0; pq < 8; ++pq) sum += red[tid * 8 + pq];
        feats[(size_t)pos * NTAG + tid] = sum;
    }
}

// ---------------- kernel D: Viterbi forward + chunked backtrace ----------------
__launch_bounds__(256)
__global__ void viterbi_kernel(const float* __restrict__ feats, const float* __restrict__ trans,
                               unsigned char* __restrict__ bptr, float* __restrict__ out)
{
    __shared__ float feat_lds[64 * NTAG];
    __shared__ int sh_best;
    __shared__ unsigned char Mmap[8][NTAG];
    __shared__ unsigned char entry_s[8];
    const int tid = threadIdx.x;

    if (tid < 64) {
        const int lane = tid;
        const int i = (lane < NTAG) ? lane : (NTAG - 1);
        float trow[NTAG];
        #pragma unroll
        for (int jj = 0; jj < NTAG; ++jj) trow[jj] = trans[i * NTAG + jj];
        float fv[NTAG];
        #pragma unroll
        for (int jj = 0; jj < NTAG; ++jj) fv[jj] = (jj == 18) ? 0.f : NEGV;

        for (int blk = 0; blk < 64; ++blk) {
            #pragma unroll
            for (int q = 0; q < 20; ++q)
                feat_lds[q * 64 + lane] = feats[blk * 1280 + q * 64 + lane];
            for (int ss = 0; ss < 64; ++ss) {
                int s = blk * 64 + ss;
                float best = fv[0] + trow[0];
                int bj = 0;
                #pragma unroll
                for (int jj = 1; jj < NTAG; ++jj) {
                    float cand = fv[jj] + trow[jj];
                    if (cand > best) { best = cand; bj = jj; }   // strict >: first-max tie rule
                }
                float fnew = best + feat_lds[ss * NTAG + i];
                if (lane < NTAG) bptr[s * NTAG + lane] = (unsigned char)bj;
                #pragma unroll
                for (int jj = 0; jj < NTAG; ++jj) fv[jj] = __shfl(fnew, jj);
            }
        }
        if (lane == 0) {
            float best = -1e30f; int bt = 0;
            for (int jj = 0; jj < NTAG; ++jj) {
                float t2 = fv[jj] + trans[TAG_STOP * NTAG + jj];
                if (t2 > best) { best = t2; bt = jj; }
            }
            out[0] = best;
            sh_best = bt;
        }
    }
    __syncthreads();
    if (tid < 160) {
        int c = tid / NTAG, e = tid % NTAG;
        int tag = e;
        for (int t = (c + 1) * 512 - 1; t >= c * 512; --t) tag = bptr[t * NTAG + tag];
        Mmap[c][e] = (unsigned char)tag;
    }
    __syncthreads();
    if (tid == 0) {
        int e = sh_best;
        entry_s[7] = (unsigned char)e;
        for (int c = 7; c >= 1; --c) { e = Mmap[c][e]; entry_s[c - 1] = (unsigned char)e; }
    }
    __syncthreads();
    if (tid < 8) {
        int c = tid;
        int tag = entry_s[c];
        out[1 + (c + 1) * 512 - 1] = (float)tag;
        for (int t = (c + 1) * 512 - 1; t > c * 512; --t) {
            tag = bptr[t * NTAG + tag];
            out[1 + t - 1] = (float)tag;
        }
    }
}

extern "C" void kernel_launch(void* const* d_in, const int* in_sizes, int n_in,
                              void* d_out, int out_size, void* d_ws, size_t ws_size,
                              hipStream_t stream) {
    (void)in_sizes; (void)n_in; (void)out_size; (void)ws_size;
    const int*   sent  = (const int*)d_in[0];
    const float* embed = (const float*)d_in[1];
    const float* wihf  = (const float*)d_in[2];
    const float* whhf  = (const float*)d_in[3];
    const float* bihf  = (const float*)d_in[4];
    const float* bhhf  = (const float*)d_in[5];
    const float* wihb  = (const float*)d_in[6];
    const float* whhb  = (const float*)d_in[7];
    const float* bihb  = (const float*)d_in[8];
    const float* bihb2 = (const float*)d_in[9];
    const float* wout  = (const float*)d_in[10];
    const float* bout  = (const float*)d_in[11];
    const float* trans = (const float*)d_in[12];
    const float* h0    = (const float*)d_in[13];
    const float* c0    = (const float*)d_in[14];
    const float* bhhb  = bihb2;

    char* ws = (char*)d_ws;
    unsigned long long* h_pub = (unsigned long long*)(ws + 4096);   // 16 KB
    float* pre   = (float*)(ws + 65536);
    float* hs    = (float*)(ws + 65536 + (size_t)4096 * 4096 * 4);
    float* feats = (float*)(ws + 65536 + (size_t)4096 * 4096 * 4 + (size_t)2 * 4096 * 512 * 4);
    unsigned char* bptr = (unsigned char*)(feats + (size_t)S_LEN * NTAG);
    float* out = (float*)d_out;

    hipLaunchKernelGGL(init_ws, dim3(8), dim3(256), 0, stream, h_pub);
    hipLaunchKernelGGL(pre_gemm, dim3(2048), dim3(256), 0, stream,
                       sent, embed, wihf, wihb, bihf, bhhf, bihb, bhhb, pre);
    hipLaunchKernelGGL(lstm_kernel, dim3(32), dim3(512), 0, stream,
                       pre, whhf, whhb, h0, c0, hs, h_pub);
    hipLaunchKernelGGL(feats_kernel, dim3(S_LEN), dim3(256), 0, stream,
                       hs, wout, bout, feats);
    hipLaunchKernelGGL(viterbi_kernel, dim3(1), dim3(256), 0, stream,
                       feats, trans, bptr, out);
}

// Round 7
// 10352.089 us; speedup vs baseline: 1.1171x; 1.0871x over previous
//
#include <hip/hip_runtime.h>
#include <math.h>

#define S_LEN 4096
#define NTAG 20
#define TAG_STOP 19
#define NEGV -10000.0f

// ---------------- workspace layout (bytes) ----------------
// [0,256)          uint ready[64]         (per-64-pos pre-tile completion counters, -> 32)
// [4096,20480)     ull h_pub[2][2][512]   (dir, parity, unit) packed {seq32|h32}
// [65536, +64MB)   float pre[4096][4096]  (pos, row; rows 0..2047 fwd, 2048..4095 bwd)
// then             float hs[2][4096][512]
// then             float feats[4096][20]
// then             u8 bptr[4096*20]

__global__ void init_ws(unsigned int* ready, unsigned long long* hpub) {
    int i = blockIdx.x * 256 + threadIdx.x;
    if (i < 64) ready[i] = 0u;
    if (i < 2048) hpub[i] = 0ull;
}

__device__ __forceinline__ float sigm(float x) { return 1.0f / (1.0f + expf(-x)); }

__device__ __forceinline__ unsigned long long agent_ld(const unsigned long long* p) {
    return __hip_atomic_load(p, __ATOMIC_RELAXED, __HIP_MEMORY_SCOPE_AGENT);
}

__device__ __forceinline__ void tile_wait(const unsigned int* ready, unsigned int& rdy_tile, int t) {
    if ((unsigned int)t != rdy_tile) {
        while (__hip_atomic_load(&ready[t], __ATOMIC_ACQUIRE, __HIP_MEMORY_SCOPE_AGENT) < 32u)
            __builtin_amdgcn_s_sleep(4);
        rdy_tile = (unsigned int)t;
    }
}

// ---------------- one LSTM step (P = s&1, compile-time) — exact R3 body + tile gating ----------------
template<int P>
__device__ __forceinline__ void lstm_step(
    int s, int dir, int wg, int j, int ks, int su, bool own, int sidx, bool gate,
    const float* __restrict__ pre, const float* __restrict__ h0,
    float* __restrict__ hs, unsigned long long* pub,
    const unsigned int* __restrict__ ready, unsigned int& rdy_tile,
    float (&buf)[2][576],
    const float (&wr0)[32], const float (&wr1)[32],
    const float (&wr2)[32], const float (&wr3)[32],
    float (&pf)[4], float& c_reg)
{
    // ---- stage h_{s-1} into buf[P]: one 8B data-is-flag poll per thread ----
    if (s == 0) {
        buf[0][sidx] = h0[dir * 512 + su];
    } else if (!own) {
        const unsigned int expect = (unsigned int)s;
        const unsigned long long* p = &pub[P * 512 + su];
        unsigned long long u = agent_ld(p);
        while ((unsigned int)(u >> 32) < expect) u = agent_ld(p);
        buf[P][sidx] = __uint_as_float((unsigned int)u);
    }
    __syncthreads();   // the only barrier per step

    // ---- matvec: 4 gate rows x 32 k per lane, weights register-resident ----
    float a0 = 0.f, a1 = 0.f, a2 = 0.f, a3 = 0.f;
    const float* hp = &buf[P][ks * 36];
    #pragma unroll
    for (int q = 0; q < 8; ++q) {
        float4 h4 = ((const float4*)hp)[q];
        a0 += wr0[q*4+0]*h4.x + wr0[q*4+1]*h4.y + wr0[q*4+2]*h4.z + wr0[q*4+3]*h4.w;
        a1 += wr1[q*4+0]*h4.x + wr1[q*4+1]*h4.y + wr1[q*4+2]*h4.z + wr1[q*4+3]*h4.w;
        a2 += wr2[q*4+0]*h4.x + wr2[q*4+1]*h4.y + wr2[q*4+2]*h4.z + wr2[q*4+3]*h4.w;
        a3 += wr3[q*4+0]*h4.x + wr3[q*4+1]*h4.y + wr3[q*4+2]*h4.z + wr3[q*4+3]*h4.w;
    }
    // ---- 16-lane butterfly reduce over k-slices ----
    a0 += __shfl_xor(a0, 1); a0 += __shfl_xor(a0, 2); a0 += __shfl_xor(a0, 4); a0 += __shfl_xor(a0, 8);
    a1 += __shfl_xor(a1, 1); a1 += __shfl_xor(a1, 2); a1 += __shfl_xor(a1, 4); a1 += __shfl_xor(a1, 8);
    a2 += __shfl_xor(a2, 1); a2 += __shfl_xor(a2, 2); a2 += __shfl_xor(a2, 4); a2 += __shfl_xor(a2, 8);
    a3 += __shfl_xor(a3, 1); a3 += __shfl_xor(a3, 2); a3 += __shfl_xor(a3, 4); a3 += __shfl_xor(a3, 8);

    // ---- gates + publish (lane ks==0 of each 16-group: 1 unit) ----
    if (gate) {
        float gi = a0 + pf[0], gf = a1 + pf[1], gg = a2 + pf[2], go = a3 + pf[3];
        float cn = sigm(gf) * c_reg + sigm(gi) * tanhf(gg);
        float hN = sigm(go) * tanhf(cn);
        c_reg = cn;
        const int pos = dir ? (S_LEN - 1 - s) : s;
        hs[((size_t)dir * S_LEN + pos) * 512 + j] = hN;
        buf[P ^ 1][j + 4 * wg] = hN;                    // own-unit fast path (next parity)
        unsigned long long uv = ((unsigned long long)(unsigned int)(s + 1) << 32)
                              | (unsigned long long)__float_as_uint(hN);
        __hip_atomic_store(&pub[(P ^ 1) * 512 + j], uv,
                           __ATOMIC_RELAXED, __HIP_MEMORY_SCOPE_AGENT);
        // ---- distance-2 pre prefetch for step s+2 (gated on tile readiness) ----
        if (s + 2 < S_LEN) {
            const int pp = dir ? (S_LEN - 3 - s) : (s + 2);
            tile_wait(ready, rdy_tile, pp >> 6);
            const float* pb = pre + (size_t)pp * 4096 + dir * 2048 + j;
            pf[0] = pb[0]; pf[1] = pb[512]; pf[2] = pb[1024]; pf[3] = pb[1536];
        }
    }
}

// ---------------- fused kernel: blocks 0..31 = BiLSTM, blocks 32..2079 = pre-GEMM ----------------
// GEMM role (512 thr): tile BM=64 pos x BN=128 rows, BK=16, 4x4 micro-tile.
// pre written via agent-scope write-through stores; ready[bm] release-incremented
// per finished (bm,bn) tile. bm order interleaved from both ends (0,63,1,62,...)
// so both LSTM directions' first tiles complete in the first dispatch round.
// LSTM role: exact R3 structure (32 blocks x 512 thr, data-is-flag 8B poll,
// one barrier/step); gate lanes gate their pre-prefetch on ready[] (monotone,
// 64 one-time acquire-checks over the whole sequence).
__launch_bounds__(512, 2)
__global__ void fused_kernel(const int* __restrict__ sent, const float* __restrict__ embed,
                             const float* __restrict__ wf, const float* __restrict__ wb,
                             const float* __restrict__ bihf, const float* __restrict__ bhhf,
                             const float* __restrict__ bihb, const float* __restrict__ bhhb,
                             float* __restrict__ pre,
                             const float* __restrict__ w_hh_f, const float* __restrict__ w_hh_b,
                             const float* __restrict__ h0, const float* __restrict__ c0,
                             float* __restrict__ hs, unsigned long long* __restrict__ h_pub,
                             unsigned int* __restrict__ ready)
{
    __shared__ float As[16][68];
    __shared__ float Bs[16][136];
    __shared__ int   srow[64];
    __shared__ float buf[2][576];
    const int tid = threadIdx.x;

    if (blockIdx.x >= 32) {
        // ================= GEMM role =================
        const int gq = blockIdx.x - 32;
        const int q  = gq >> 5;
        const int bn = gq & 31;
        const int bm = (q & 1) ? (63 - (q >> 1)) : (q >> 1);
        const int pos0 = bm * 64, row0 = bn * 128;
        if (tid < 64) srow[tid] = sent[pos0 + tid];
        __syncthreads();

        const int ty = tid >> 5, tx = tid & 31;
        float acc[4][4];
        #pragma unroll
        for (int m = 0; m < 4; ++m)
            #pragma unroll
            for (int n = 0; n < 4; ++n) acc[m][n] = 0.f;

        for (int kt = 0; kt < 1024; kt += 16) {
            if (tid < 256) {   // A tile: 64 pos x 16 k
                int m = tid >> 2, kc = (tid & 3) * 4;
                float4 v = *(const float4*)(embed + (size_t)srow[m] * 1024 + kt + kc);
                As[kc+0][m] = v.x; As[kc+1][m] = v.y; As[kc+2][m] = v.z; As[kc+3][m] = v.w;
            }
            {   // B tile: 128 rows x 16 k (each thread one float4)
                int n = tid >> 2, kc = (tid & 3) * 4;
                int grow = row0 + n;
                const float* wsrc = (grow < 2048) ? (wf + (size_t)grow * 1024)
                                                  : (wb + (size_t)(grow - 2048) * 1024);
                float4 v = *(const float4*)(wsrc + kt + kc);
                Bs[kc+0][n] = v.x; Bs[kc+1][n] = v.y; Bs[kc+2][n] = v.z; Bs[kc+3][n] = v.w;
            }
            __syncthreads();
            #pragma unroll
            for (int kk = 0; kk < 16; ++kk) {
                float4 av = *(const float4*)&As[kk][ty * 4];
                float4 bv = *(const float4*)&Bs[kk][tx * 4];
                float a[4] = {av.x, av.y, av.z, av.w};
                float b[4] = {bv.x, bv.y, bv.z, bv.w};
                #pragma unroll
                for (int m = 0; m < 4; ++m)
                    #pragma unroll
                    for (int n = 0; n < 4; ++n) acc[m][n] += a[m] * b[n];
            }
            __syncthreads();
        }
        #pragma unroll
        for (int m = 0; m < 4; ++m) {
            int pos = pos0 + ty * 4 + m;
            #pragma unroll
            for (int n = 0; n < 4; ++n) {
                int grow = row0 + tx * 4 + n;
                float bias = (grow < 2048) ? (bihf[grow] + bhhf[grow])
                                           : (bihb[grow - 2048] + bhhb[grow - 2048]);
                // write-through to coherence point (L3): visible to LSTM blocks cross-XCD
                __hip_atomic_store(&pre[(size_t)pos * 4096 + grow], acc[m][n] + bias,
                                   __ATOMIC_RELAXED, __HIP_MEMORY_SCOPE_AGENT);
            }
        }
        __syncthreads();   // vmcnt(0) drain: all tile stores at coherence point
        if (tid == 0)
            __hip_atomic_fetch_add(&ready[bm], 1u, __ATOMIC_RELEASE, __HIP_MEMORY_SCOPE_AGENT);
        return;
    }

    // ================= LSTM role (exact R3 structure) =================
    const int dir  = blockIdx.x >> 4;
    const int wg   = blockIdx.x & 15;
    const int wv   = tid >> 6;
    const int lane = tid & 63;
    const int rg   = lane >> 4;
    const int ks   = lane & 15;
    const int j    = wg * 32 + wv * 4 + rg;        // this lane-group's global unit
    const float* w_hh = dir ? w_hh_b : w_hh_f;

    // ---- weights: 4 gate rows (g*512+j) x 32 k (ks slice), 128 f32 ----
    float wr0[32], wr1[32], wr2[32], wr3[32];
    {
        const float* wbase = w_hh + (size_t)j * 512 + ks * 32;
        #pragma unroll
        for (int qq = 0; qq < 8; ++qq) {
            float4 v0 = *(const float4*)(wbase + 0 * 262144 + qq * 4);
            wr0[qq*4+0] = v0.x; wr0[qq*4+1] = v0.y; wr0[qq*4+2] = v0.z; wr0[qq*4+3] = v0.w;
            float4 v1 = *(const float4*)(wbase + 1 * 262144 + qq * 4);
            wr1[qq*4+0] = v1.x; wr1[qq*4+1] = v1.y; wr1[qq*4+2] = v1.z; wr1[qq*4+3] = v1.w;
            float4 v2 = *(const float4*)(wbase + 2 * 262144 + qq * 4);
            wr2[qq*4+0] = v2.x; wr2[qq*4+1] = v2.y; wr2[qq*4+2] = v2.z; wr2[qq*4+3] = v2.w;
            float4 v3 = *(const float4*)(wbase + 3 * 262144 + qq * 4);
            wr3[qq*4+0] = v3.x; wr3[qq*4+1] = v3.y; wr3[qq*4+2] = v3.z; wr3[qq*4+3] = v3.w;
        }
    }

    const bool gate = (ks == 0);
    unsigned int rdy_tile = 0xffffffffu;
    float c_reg = 0.f;
    float pfA[4] = {0,0,0,0}, pfB[4] = {0,0,0,0};
    if (gate) {
        c_reg = c0[dir * 512 + j];
        const int p0 = dir ? (S_LEN - 1) : 0;
        const int p1 = dir ? (S_LEN - 2) : 1;
        tile_wait(ready, rdy_tile, p0 >> 6);
        tile_wait(ready, rdy_tile, p1 >> 6);   // same tile in practice; cheap
        const float* b0 = pre + (size_t)p0 * 4096 + dir * 2048 + j;
        const float* b1 = pre + (size_t)p1 * 4096 + dir * 2048 + j;
        pfA[0] = b0[0]; pfA[1] = b0[512]; pfA[2] = b0[1024]; pfA[3] = b0[1536];
        pfB[0] = b1[0]; pfB[1] = b1[512]; pfB[2] = b1[1024]; pfB[3] = b1[1536];
    }

    const int  su   = tid;                       // unit staged by this thread
    const bool own  = ((su >> 5) == wg);         // own units come via LDS fast path
    const int  sidx = su + ((su >> 5) << 2);     // padded LDS index
    unsigned long long* pub = h_pub + dir * 1024;

    for (int s = 0; s < S_LEN; s += 2) {
        lstm_step<0>(s,     dir, wg, j, ks, su, own, sidx, gate,
                     pre, h0, hs, pub, ready, rdy_tile, buf, wr0, wr1, wr2, wr3, pfA, c_reg);
        lstm_step<1>(s + 1, dir, wg, j, ks, su, own, sidx, gate,
                     pre, h0, hs, pub, ready, rdy_tile, buf, wr0, wr1, wr2, wr3, pfB, c_reg);
    }
}

// ---------------- kernel C: feats = concat(hf,hb) @ w_out^T + b_out ----------------
__launch_bounds__(256)
__global__ void feats_kernel(const float* __restrict__ hs, const float* __restrict__ w_out,
                             const float* __restrict__ b_out, float* __restrict__ feats)
{
    const int pos = blockIdx.x;
    const int tid = threadIdx.x;
    __shared__ float hbuf[1024];
    __shared__ float red[160];
    {
        const float* hf = hs + (size_t)pos * 512;
        const float* hb = hs + ((size_t)S_LEN + pos) * 512;
        if (tid < 128) *(float4*)&hbuf[tid * 4]           = *(const float4*)&hf[tid * 4];
        else           *(float4*)&hbuf[512 + (tid-128)*4] = *(const float4*)&hb[(tid - 128) * 4];
    }
    __syncthreads();
    if (tid < 160) {
        int tag = tid >> 3, part = tid & 7;
        const float* wrow = w_out + (size_t)tag * 1024 + part * 128;
        const float* hrow = hbuf + part * 128;
        float sum = 0.f;
        #pragma unroll
        for (int q = 0; q < 32; ++q) {
            float4 a = ((const float4*)hrow)[q];
            float4 b = ((const float4*)wrow)[q];
            sum += a.x*b.x + a.y*b.y + a.z*b.z + a.w*b.w;
        }
        red[tid] = sum;
    }
    __syncthreads();
    if (tid < NTAG) {
        float sum = b_out[tid];
        #pragma unroll
        for (int pq = 0; pq < 8; ++pq) sum += red[tid * 8 + pq];
        feats[(size_t)pos * NTAG + tid] = sum;
    }
}

// ---------------- kernel D: Viterbi forward + chunked backtrace ----------------
__launch_bounds__(256)
__global__ void viterbi_kernel(const float* __restrict__ feats, const float* __restrict__ trans,
                               unsigned char* __restrict__ bptr, float* __restrict__ out)
{
    __shared__ float feat_lds[64 * NTAG];
    __shared__ int sh_best;
    __shared__ unsigned char Mmap[8][NTAG];
    __shared__ unsigned char entry_s[8];
    const int tid = threadIdx.x;

    if (tid < 64) {
        const int lane = tid;
        const int i = (lane < NTAG) ? lane : (NTAG - 1);
        float trow[NTAG];
        #pragma unroll
        for (int jj = 0; jj < NTAG; ++jj) trow[jj] = trans[i * NTAG + jj];
        float fv[NTAG];
        #pragma unroll
        for (int jj = 0; jj < NTAG; ++jj) fv[jj] = (jj == 18) ? 0.f : NEGV;

        for (int blk = 0; blk < 64; ++blk) {
            #pragma unroll
            for (int q = 0; q < 20; ++q)
                feat_lds[q * 64 + lane] = feats[blk * 1280 + q * 64 + lane];
            for (int ss = 0; ss < 64; ++ss) {
                int s = blk * 64 + ss;
                float best = fv[0] + trow[0];
                int bj = 0;
                #pragma unroll
                for (int jj = 1; jj < NTAG; ++jj) {
                    float cand = fv[jj] + trow[jj];
                    if (cand > best) { best = cand; bj = jj; }   // strict >: first-max tie rule
                }
                float fnew = best + feat_lds[ss * NTAG + i];
                if (lane < NTAG) bptr[s * NTAG + lane] = (unsigned char)bj;
                #pragma unroll
                for (int jj = 0; jj < NTAG; ++jj) fv[jj] = __shfl(fnew, jj);
            }
        }
        if (lane == 0) {
            float best = -1e30f; int bt = 0;
            for (int jj = 0; jj < NTAG; ++jj) {
                float t2 = fv[jj] + trans[TAG_STOP * NTAG + jj];
                if (t2 > best) { best = t2; bt = jj; }
            }
            out[0] = best;
            sh_best = bt;
        }
    }
    __syncthreads();
    if (tid < 160) {
        int c = tid / NTAG, e = tid % NTAG;
        int tag = e;
        for (int t = (c + 1) * 512 - 1; t >= c * 512; --t) tag = bptr[t * NTAG + tag];
        Mmap[c][e] = (unsigned char)tag;
    }
    __syncthreads();
    if (tid == 0) {
        int e = sh_best;
        entry_s[7] = (unsigned char)e;
        for (int c = 7; c >= 1; --c) { e = Mmap[c][e]; entry_s[c - 1] = (unsigned char)e; }
    }
    __syncthreads();
    if (tid < 8) {
        int c = tid;
        int tag = entry_s[c];
        out[1 + (c + 1) * 512 - 1] = (float)tag;
        for (int t = (c + 1) * 512 - 1; t > c * 512; --t) {
            tag = bptr[t * NTAG + tag];
            out[1 + t - 1] = (float)tag;
        }
    }
}

extern "C" void kernel_launch(void* const* d_in, const int* in_sizes, int n_in,
                              void* d_out, int out_size, void* d_ws, size_t ws_size,
                              hipStream_t stream) {
    (void)in_sizes; (void)n_in; (void)out_size; (void)ws_size;
    const int*   sent  = (const int*)d_in[0];
    const float* embed = (const float*)d_in[1];
    const float* wihf  = (const float*)d_in[2];
    const float* whhf  = (const float*)d_in[3];
    const float* bihf  = (const float*)d_in[4];
    const float* bhhf  = (const float*)d_in[5];
    const float* wihb  = (const float*)d_in[6];
    const float* whhb  = (const float*)d_in[7];
    const float* bihb  = (const float*)d_in[8];
    const float* bhhb  = (const float*)d_in[9];
    const float* wout  = (const float*)d_in[10];
    const float* bout  = (const float*)d_in[11];
    const float* trans = (const float*)d_in[12];
    const float* h0    = (const float*)d_in[13];
    const float* c0    = (const float*)d_in[14];

    char* ws = (char*)d_ws;
    unsigned int* ready       = (unsigned int*)ws;
    unsigned long long* h_pub = (unsigned long long*)(ws + 4096);   // 16 KB
    float* pre   = (float*)(ws + 65536);
    float* hs    = (float*)(ws + 65536 + (size_t)4096 * 4096 * 4);
    float* feats = (float*)(ws + 65536 + (size_t)4096 * 4096 * 4 + (size_t)2 * 4096 * 512 * 4);
    unsigned char* bptr = (unsigned char*)(feats + (size_t)S_LEN * NTAG);
    float* out = (float*)d_out;

    hipLaunchKernelGGL(init_ws, dim3(8), dim3(256), 0, stream, ready, h_pub);
    hipLaunchKernelGGL(fused_kernel, dim3(32 + 2048), dim3(512), 0, stream,
                       sent, embed, wihf, wihb, bihf, bhhf, bihb, bhhb, pre,
                       whhf, whhb, h0, c0, hs, h_pub, ready);
    hipLaunchKernelGGL(feats_kernel, dim3(S_LEN), dim3(256), 0, stream,
                       hs, wout, bout, feats);
    hipLaunchKernelGGL(viterbi_kernel, dim3(1), dim3(256), 0, stream,
                       feats, trans, bptr, out);
}